// Round 23
// baseline (259.530 us; speedup 1.0000x reference)
//
#include <hip/hip_runtime.h>
#include <math.h>

#define NEG_SLOPE 0.2f
#define LN_EPS 1e-5f
#define BUCKET 48

typedef __attribute__((ext_vector_type(2))) float f32x2;

// DPP-based add: x += x permuted by CTRL (within 16-lane rows)
template <int CTRL>
__device__ __forceinline__ float dpp_add(float x) {
    int s = __builtin_amdgcn_update_dpp(0, __float_as_int(x), CTRL, 0xF, 0xF, true);
    return x + __int_as_float(s);
}
// full 16-lane row sum
__device__ __forceinline__ float row16_sum(float x) {
    x = dpp_add<0xB1>(x);   // quad_perm [1,0,3,2]
    x = dpp_add<0x4E>(x);   // quad_perm [2,3,0,1]
    x = dpp_add<0x124>(x);  // row_ror:4
    x = dpp_add<0x128>(x);  // row_ror:8
    return x;
}

// ---------- prep (FROZEN): transforms + hop-bias fold + direct bucket placement ------
__global__ __launch_bounds__(256) void prep(
    const float* __restrict__ x,
    const float* __restrict__ W_l, const float* __restrict__ b_l,
    const float* __restrict__ W_r, const float* __restrict__ b_r,
    const float* __restrict__ W_res, const float* __restrict__ b_res,
    const float* __restrict__ W_e,
    const int* __restrict__ dist, const float* __restrict__ bph,
    float* __restrict__ xl, float* __restrict__ xr, float* __restrict__ xres_out,
    const int* __restrict__ ei, int* __restrict__ counts, int2* __restrict__ bucket,
    int n, int E_) {
    __shared__ float sWl[4096];
    __shared__ float sWr[4096];
    __shared__ float sWs[4096];
    __shared__ float sx[256];
    for (int i = threadIdx.x; i < 4096; i += 256) {
        sWl[i] = W_l[i]; sWr[i] = W_r[i]; sWs[i] = W_res[i];
    }
    int lane = threadIdx.x & 63;
    int w = threadIdx.x >> 6;
    float bl = b_l[lane], br = b_r[lane], bs = b_res[lane];
    float wsum = 0.0f;
#pragma unroll
    for (int k = 0; k < 16; ++k) wsum += W_e[k * 64 + lane];
    __syncthreads();
    for (int base = blockIdx.x * 4; base < n; base += gridDim.x * 4) {
        __syncthreads();
        int r = base + w;
        if (r < n) sx[threadIdx.x] = x[(size_t)r * 64 + lane];
        __syncthreads();
        if (r < n) {
            float al = bl, ar = br, as_ = bs;
            const float* xv = &sx[w * 64];
#pragma unroll
            for (int k = 0; k < 64; ++k) {
                float xk = xv[k];
                al = fmaf(xk, sWl[k * 64 + lane], al);
                ar = fmaf(xk, sWr[k * 64 + lane], ar);
                as_ = fmaf(xk, sWs[k * 64 + lane], as_);
            }
            int hop = dist[r];
            hop = hop < 0 ? 0 : (hop > 3 ? 3 : hop);
            float hb = 0.1f * bph[hop];
            xl[(size_t)r * 64 + lane] = al;
            xr[(size_t)r * 64 + lane] = fmaf(hb, wsum, ar);  // hop bias folded in
            xres_out[(size_t)r * 64 + lane] = as_;           // residual staged in d_out
        }
    }
    // direct bucket placement
    const int* di = ei + E_;
    for (int e = blockIdx.x * 256 + threadIdx.x; e < E_; e += gridDim.x * 256) {
        int dst = di[e];
        int src = ei[e];
        int pos = atomicAdd(&counts[dst], 1);
        pos = pos < BUCKET - 1 ? pos : BUCKET - 1;  // safety clamp
        bucket[(size_t)dst * BUCKET + pos] = make_int2(e, src);
    }
}

// ---------- fused gather: 3-phase loop + node-level prefetch (entries, X, resv) ------
#define LOAD_G(G, EA)                                                       \
    {                                                                       \
        int ec = __builtin_amdgcn_readfirstlane((EA).x);                    \
        const f32x2* p = (const f32x2*)(eattr + (size_t)ec * 16);           \
        _Pragma("unroll") for (int k = 0; k < 8; ++k) G[k] = p[k];          \
    }

#define PHASE(G, X, E, DEN, ACC, I)                                         \
    {                                                                       \
        f32x2 mm; mm.x = X + base; mm.y = 0.0f;                             \
        _Pragma("unroll") for (int k = 0; k < 8; ++k)                       \
            mm = __builtin_elementwise_fma(G[k], w2[k], mm);                \
        float m = mm.x + mm.y;                                              \
        m = fmaxf(m, NEG_SLOPE * m);                                        \
        float l = row16_sum(m * attv);   /* attv pre-scaled by log2(e) */   \
        l = (I) < cc ? l : -1e30f;                                          \
        float ex = __builtin_amdgcn_exp2f(l);                               \
        DEN += ex;                                                          \
        ACC = fmaf(ex, X, ACC);                                             \
        X = xl[((unsigned)(E).y << 6) | lane];                              \
        LOAD_G(G, E);                                                       \
        int nx = (I) + 6; nx = nx > last ? last : nx;                       \
        E = bk[nx];                                                         \
    }

__global__ __launch_bounds__(256) void fused_gather(
    const int* __restrict__ counts, const int2* __restrict__ bucket,
    const float* __restrict__ eattr,
    const float* __restrict__ W_e, const float* __restrict__ att,
    const float* __restrict__ xl, const float* __restrict__ xr,
    const float* __restrict__ bias,
    const float* __restrict__ gamma, const float* __restrict__ beta,
    float* out, int n) {
    int lane = threadIdx.x & 63;
    float attv = att[lane] * 1.44269504f;  // log2(e) folded: exp -> exp2
    float bi = bias[lane], g = gamma[lane], be = beta[lane];
    f32x2 w2[8];
#pragma unroll
    for (int k = 0; k < 8; ++k) {
        w2[k].x = W_e[(2 * k) * 64 + lane];
        w2[k].y = W_e[(2 * k + 1) * 64 + lane];
    }

    int wid = (blockIdx.x * blockDim.x + threadIdx.x) >> 6;
    int nw = (gridDim.x * blockDim.x) >> 6;
    if (wid >= n) return;
    int r = wid;
    int cc, last;
    float base, resv;
    int2 A0, A1, A2, E0, E1, E2;
    float X0, X1, X2;
    // first-node prologue: entries, sanitize, X loads, resv
    {
        int cnt = counts[r];
        base = xr[((unsigned)r << 6) | lane];
        resv = out[((unsigned)r << 6) | lane];
        const int2* bkp = bucket + (size_t)r * BUCKET;
        A0 = bkp[0]; A1 = bkp[1]; A2 = bkp[2];
        E0 = bkp[3]; E1 = bkp[4]; E2 = bkp[5];
        cc = cnt < BUCKET ? cnt : BUCKET;
        last = cc - 1;
        int2 Z = make_int2(0, 0);
        A0 = cc > 0 ? A0 : Z;
        A1 = last >= 1 ? A1 : A0;
        A2 = last >= 2 ? A2 : A0;
        E0 = last >= 3 ? E0 : A0;
        E1 = last >= 4 ? E1 : A0;
        E2 = last >= 5 ? E2 : A0;
        X0 = xl[((unsigned)A0.y << 6) | lane];
        X1 = xl[((unsigned)A1.y << 6) | lane];
        X2 = xl[((unsigned)A2.y << 6) | lane];
    }
    for (;;) {
        const int2* bk = bucket + (size_t)r * BUCKET;
        // current node's G s_loads (entries already sanitized in registers)
        f32x2 G0[8], G1[8], G2[8];
        LOAD_G(G0, A0);
        LOAD_G(G1, A1);
        LOAD_G(G2, A2);
        // prefetch next node's full prologue (overlaps this node's edge loop)
        int rn = r + nw;
        int hn = rn < n;
        int rc = hn ? rn : r;
        int cntn = counts[rc];
        float basen = xr[((unsigned)rc << 6) | lane];
        float resvn = out[((unsigned)rc << 6) | lane];
        int ccn, lastn;
        int2 An0, An1, An2, En0, En1, En2;
        float Xn0, Xn1, Xn2;
        {
            const int2* bkn = bucket + (size_t)rc * BUCKET;
            An0 = bkn[0]; An1 = bkn[1]; An2 = bkn[2];
            En0 = bkn[3]; En1 = bkn[4]; En2 = bkn[5];
            ccn = cntn < BUCKET ? cntn : BUCKET;
            lastn = ccn - 1;
            int2 Z = make_int2(0, 0);
            An0 = ccn > 0 ? An0 : Z;
            An1 = lastn >= 1 ? An1 : An0;
            An2 = lastn >= 2 ? An2 : An0;
            En0 = lastn >= 3 ? En0 : An0;
            En1 = lastn >= 4 ? En1 : An0;
            En2 = lastn >= 5 ? En2 : An0;
            Xn0 = xl[((unsigned)An0.y << 6) | lane];
            Xn1 = xl[((unsigned)An1.y << 6) | lane];
            Xn2 = xl[((unsigned)An2.y << 6) | lane];
        }
        // edge loop (proven 3-phase form)
        float den0 = 0.0f, den1 = 0.0f, den2 = 0.0f;
        float acc0 = 0.0f, acc1 = 0.0f, acc2 = 0.0f;
        for (int i = 0; i < cc; i += 3) {
            PHASE(G0, X0, E0, den0, acc0, i)
            PHASE(G1, X1, E1, den1, acc1, i + 1)
            PHASE(G2, X2, E2, den2, acc2, i + 2)
        }
        float den = (den0 + den1) + den2;
        float acc = (acc0 + acc1) + acc2;
        float v = acc / (den + 1e-16f) + bi;
        // LayerNorm over 64 features
        float s = row16_sum(v);
        s += __shfl_xor(s, 16, 64);
        s += __shfl_xor(s, 32, 64);
        float mu = s * (1.0f / 64.0f);
        float dd = v - mu;
        float q = row16_sum(dd * dd);
        q += __shfl_xor(q, 16, 64);
        q += __shfl_xor(q, 32, 64);
        float var = q * (1.0f / 64.0f);
        float nv = dd * rsqrtf(var + LN_EPS) * g + be;
        out[((unsigned)r << 6) | lane] = nv + resv;  // resv prefetched at node start
        if (!hn) break;
        // rotate prefetched state in
        r = rn; cc = ccn; last = lastn; base = basen; resv = resvn;
        A0 = An0; A1 = An1; A2 = An2;
        E0 = En0; E1 = En1; E2 = En2;
        X0 = Xn0; X1 = Xn1; X2 = Xn2;
    }
}

extern "C" void kernel_launch(void* const* d_in, const int* in_sizes, int n_in,
                              void* d_out, int out_size, void* d_ws, size_t ws_size,
                              hipStream_t stream) {
    const float* x     = (const float*)d_in[0];
    const int*   ei    = (const int*)d_in[1];
    const float* eattr = (const float*)d_in[2];
    const int*   dist  = (const int*)d_in[3];
    const float* W_l   = (const float*)d_in[4];
    const float* b_l   = (const float*)d_in[5];
    const float* W_r   = (const float*)d_in[6];
    const float* b_r   = (const float*)d_in[7];
    const float* W_e   = (const float*)d_in[8];
    const float* att   = (const float*)d_in[9];
    const float* bias  = (const float*)d_in[10];
    const float* gamma = (const float*)d_in[11];
    const float* beta  = (const float*)d_in[12];
    const float* W_res = (const float*)d_in[13];
    const float* b_res = (const float*)d_in[14];
    const float* bph   = (const float*)d_in[15];

    int n  = in_sizes[0] / 64;
    int E_ = in_sizes[1] / 2;
    float* out = (float*)d_out;

    char* ws = (char*)d_ws;
    float* xl     = (float*)ws; ws += (size_t)n * 64 * 4;
    float* xr     = (float*)ws; ws += (size_t)n * 64 * 4;
    int2*  bucket = (int2*)ws;  ws += (size_t)n * BUCKET * 8;
    int*   counts = (int*)ws;   ws += (size_t)n * 4;

    hipMemsetAsync(counts, 0, (size_t)n * 4, stream);
    prep<<<2048, 256, 0, stream>>>(x, W_l, b_l, W_r, b_r, W_res, b_res, W_e,
                                   dist, bph, xl, xr, out, ei, counts, bucket, n, E_);
    fused_gather<<<4096, 256, 0, stream>>>(counts, bucket, eattr,
                                           W_e, att, xl, xr,
                                           bias, gamma, beta, out, n);
}